// Round 4
// baseline (98.429 us; speedup 1.0000x reference)
//
#include <hip/hip_runtime.h>

// Quantize x to nearest codeword on the fixed grid g_j = j - 7.5, j in [0,16).
// Reference: scores s_j = 2.0f * fl(x*g_j) - g_j^2, argmax with first-max
// tie-break. We replicate that bit-exactly but only over the 3-candidate
// window {f-1, f, f+1} where f = clamp(floor(x+8), 0, 15):
//   - fp32 score error <= ~3e-5 << 2.0 (min exact-score gap to any
//     non-adjacent codeword), so the fp argmax winner is adjacent to the
//     exact-nearest cell;
//   - floor(fl(x+8)) differs from the exact cell by at most +1 (only when x
//     is within ~5e-7 of the upper boundary), and the window still covers;
//   - candidates evaluated in ascending j with strict '>' keeps the FIRST
//     max, matching jnp.argmax (boundary ties pick the lower j);
//   - g^2 is exactly representable (<= 56.25), and contraction of
//     2.0f*(x*g) - g*g is bit-neutral (2*t exact, g*g exact), so scores are
//     bit-identical to the reference's.

typedef float vfloat4 __attribute__((ext_vector_type(4)));

// Returns the winning codeword g = idx - 7.5 (value output); index = g + 7.5.
__device__ __forceinline__ float quant1(float x) {
    float t = x + 8.0f;
    float f = floorf(t);
    f = fminf(fmaxf(f, 0.0f), 15.0f);        // cell index as float, integral
    float gm = fmaxf(f - 8.5f, -7.5f);       // g of candidate j-1 (clamped)
    float g0 = f - 7.5f;                     // g of candidate j
    float gp = fminf(f - 6.5f, 7.5f);        // g of candidate j+1 (clamped)
    float sm = 2.0f * (x * gm) - gm * gm;
    float s0 = 2.0f * (x * g0) - g0 * g0;
    float sp = 2.0f * (x * gp) - gp * gp;
    float best = sm, bg = gm;
    if (s0 > best) { best = s0; bg = g0; }   // strict >: ties keep lower j
    if (sp > best) { best = sp; bg = gp; }
    return bg;
}

__global__ __launch_bounds__(256) void quant4_kernel(const vfloat4* __restrict__ x4,
                                                     vfloat4* __restrict__ val4,
                                                     vfloat4* __restrict__ idx4,
                                                     int nquads) {
    int i = blockIdx.x * blockDim.x + threadIdx.x;
    if (i >= nquads) return;
    vfloat4 x = __builtin_nontemporal_load(&x4[i]);
    vfloat4 v, f;
    v.x = quant1(x.x);
    v.y = quant1(x.y);
    v.z = quant1(x.z);
    v.w = quant1(x.w);
    f = v + 7.5f;                            // index as float, exact
    __builtin_nontemporal_store(v, &val4[i]);
    __builtin_nontemporal_store(f, &idx4[i]);
}

__global__ void quant_tail_kernel(const float* __restrict__ x,
                                  float* __restrict__ val,
                                  float* __restrict__ idxf,
                                  int start, int n) {
    int i = start + blockIdx.x * blockDim.x + threadIdx.x;
    if (i >= n) return;
    float v = quant1(x[i]);
    val[i] = v;
    idxf[i] = v + 7.5f;
}

extern "C" void kernel_launch(void* const* d_in, const int* in_sizes, int n_in,
                              void* d_out, int out_size, void* d_ws, size_t ws_size,
                              hipStream_t stream) {
    const float* X = (const float*)d_in[0];
    float* out = (float*)d_out;
    const int n = in_sizes[0];          // 8,388,608
    float* vals = out;                  // first n floats: quantized values
    float* idxf = out + n;              // next n floats: indices (as float)

    const int nquads = n / 4;
    const int block = 256;
    const int grid = (nquads + block - 1) / block;   // 8192 blocks at n=8.4M
    quant4_kernel<<<grid, block, 0, stream>>>(
        (const vfloat4*)X, (vfloat4*)vals, (vfloat4*)idxf, nquads);

    const int rem = n - nquads * 4;
    if (rem > 0) {
        quant_tail_kernel<<<1, 64, 0, stream>>>(X, vals, idxf, nquads * 4, n);
    }
}